// Round 1
// baseline (2236.323 us; speedup 1.0000x reference)
//
#include <hip/hip_runtime.h>
#include <hip/hip_bf16.h>

// Problem constants (from reference)
#define BB 4
#define NN 2000
#define KK 32
#define HH 128
constexpr int   SS   = 132;      // padded LDS row stride (floats): 132*4B -> +1 bank per row pair
constexpr float EPSF = 1e-6f;
constexpr float INV_SCALE = 1.0f / 30.0f;

__device__ __forceinline__ float bf2f(unsigned short u) {
  union { unsigned int i; float f; } v; v.i = ((unsigned int)u) << 16; return v.f;
}
__device__ __forceinline__ unsigned short f2bf(float f) {
  union { float f; unsigned int i; } v; v.f = f;
  unsigned int x = v.i;
  return (unsigned short)((x + 0x7FFFu + ((x >> 16) & 1u)) >> 16);
}

// Accumulate acc[r][c] += sum_i lds[(r0+r)*SS + i] * Wp[i*HH + (c0 + 64*c)]
// lds: [32][SS] staged activations (rows = edges), Wp: [128][128] row-major slice.
// Thread layout: c0 = t&63 (cols c0, c0+64), rg = t>>6 (rows rg*8 .. rg*8+7).
__device__ __forceinline__ void gemm_acc(const float* __restrict__ lds,
                                         const float* __restrict__ Wp,
                                         int c0, int r0, float acc[8][2]) {
  for (int i = 0; i < HH; i += 4) {
    const float w00 = Wp[(i + 0) * HH + c0], w01 = Wp[(i + 0) * HH + c0 + 64];
    const float w10 = Wp[(i + 1) * HH + c0], w11 = Wp[(i + 1) * HH + c0 + 64];
    const float w20 = Wp[(i + 2) * HH + c0], w21 = Wp[(i + 2) * HH + c0 + 64];
    const float w30 = Wp[(i + 3) * HH + c0], w31 = Wp[(i + 3) * HH + c0 + 64];
#pragma unroll
    for (int r = 0; r < 8; r++) {
      const float4 a = *(const float4*)(lds + (r0 + r) * SS + i);
      acc[r][0] = fmaf(a.w, w30, fmaf(a.z, w20, fmaf(a.y, w10, fmaf(a.x, w00, acc[r][0]))));
      acc[r][1] = fmaf(a.w, w31, fmaf(a.z, w21, fmaf(a.y, w11, fmaf(a.x, w01, acc[r][1]))));
    }
  }
}

// Fused row-projection + LayerNorm: out_row = LN(X_row @ W + bias; gam, bet).
// 32 rows per block, 256 threads.
template <bool OUT_BF16>
__global__ __launch_bounds__(256) void proj_ln_kernel(
    const float* __restrict__ X, const float* __restrict__ W,
    const float* __restrict__ bias, const float* __restrict__ gam,
    const float* __restrict__ bet, void* __restrict__ outp) {
  __shared__ float seg[KK * SS];
  __shared__ float yb[KK * SS];
  const int t = threadIdx.x;
  const size_t row0 = (size_t)blockIdx.x * KK;

  {
    const int r = t >> 3, g8 = t & 7;
    const float* src = X + (row0 + r) * HH;
    float* dst = seg + r * SS;
#pragma unroll
    for (int ii = 0; ii < 4; ii++) {
      const int c = (g8 + 8 * ii) * 4;
      *(float4*)(dst + c) = *(const float4*)(src + c);
    }
  }
  __syncthreads();

  const int c0 = t & 63, rg = t >> 6, r0 = rg * 8;
  float acc[8][2];
  {
    const float b0 = bias[c0], b1v = bias[c0 + 64];
#pragma unroll
    for (int r = 0; r < 8; r++) { acc[r][0] = b0; acc[r][1] = b1v; }
  }
  gemm_acc(seg, W, c0, r0, acc);
#pragma unroll
  for (int r = 0; r < 8; r++) {
    yb[(r0 + r) * SS + c0]      = acc[r][0];
    yb[(r0 + r) * SS + c0 + 64] = acc[r][1];
  }
  __syncthreads();

  // LayerNorm per row: 8 threads per row
  const int r = t >> 3, g8 = t & 7;
  float s = 0.f, q = 0.f;
#pragma unroll
  for (int ii = 0; ii < 4; ii++) {
    const int c = (g8 + 8 * ii) * 4;
    const float4 y = *(const float4*)(yb + r * SS + c);
    s += y.x + y.y + y.z + y.w;
    q += y.x * y.x + y.y * y.y + y.z * y.z + y.w * y.w;
  }
  s += __shfl_xor(s, 1); q += __shfl_xor(q, 1);
  s += __shfl_xor(s, 2); q += __shfl_xor(q, 2);
  s += __shfl_xor(s, 4); q += __shfl_xor(q, 4);
  const float mu  = s * (1.0f / HH);
  const float var = (q - (float)HH * mu * mu) * (1.0f / (HH - 1));
  const float inv = 1.0f / (sqrtf(var + EPSF) + EPSF);

#pragma unroll
  for (int ii = 0; ii < 4; ii++) {
    const int c = (g8 + 8 * ii) * 4;
    const float4 y = *(const float4*)(yb + r * SS + c);
    float o0 = gam[c + 0] * (y.x - mu) * inv + bet[c + 0];
    float o1 = gam[c + 1] * (y.y - mu) * inv + bet[c + 1];
    float o2 = gam[c + 2] * (y.z - mu) * inv + bet[c + 2];
    float o3 = gam[c + 3] * (y.w - mu) * inv + bet[c + 3];
    if (OUT_BF16) {
      ushort4 u;
      u.x = f2bf(o0); u.y = f2bf(o1); u.z = f2bf(o2); u.w = f2bf(o3);
      *(ushort4*)((unsigned short*)outp + (row0 + r) * HH + c) = u;
    } else {
      float4 o; o.x = o0; o.y = o1; o.z = o2; o.w = o3;
      *(float4*)((float*)outp + (row0 + r) * HH + c) = o;
    }
  }
}

// One message-passing layer for one node per block.
__global__ __launch_bounds__(256) void layer_step(
    const float* __restrict__ h_in, const float* __restrict__ hS,
    const unsigned short* __restrict__ he, const int* __restrict__ E_idx,
    const float* __restrict__ mask,
    const float* __restrict__ W1, const float* __restrict__ b1,
    const float* __restrict__ W2, const float* __restrict__ b2,
    const float* __restrict__ W3, const float* __restrict__ b3,
    const float* __restrict__ gam, const float* __restrict__ bet,
    float* __restrict__ h_out) {
  __shared__ float seg[KK * SS];
  __shared__ float mA[KK * SS];
  __shared__ float hc[HH];
  __shared__ int   sidx[KK];
  __shared__ float svm[KK];
  __shared__ float partial[4 * HH];
  __shared__ float redS[4], redQ[4];

  const int t = threadIdx.x;
  const int node = blockIdx.x;
  const int bb = node / NN;
  const int bbase = bb * NN;

  if (t < KK) {
    const int ix = E_idx[(size_t)node * KK + t];
    sidx[t] = ix;
    svm[t] = mask[bbase + ix];
  }
  if (t < HH) hc[t] = h_in[(size_t)node * HH + t];
  __syncthreads();

  const int c0 = t & 63, rg = t >> 6, r0 = rg * 8;
  const int sr = t >> 3, g8 = t & 7;

  float acc[8][2];
  // Center-h quarter of the concat: identical for all K edge rows -> compute once.
  {
    float p0 = b1[c0], p1 = b1[c0 + 64];
#pragma unroll 4
    for (int i = 0; i < HH; i++) {
      const float a = hc[i];
      p0 = fmaf(a, W1[i * HH + c0], p0);
      p1 = fmaf(a, W1[i * HH + c0 + 64], p1);
    }
#pragma unroll
    for (int r = 0; r < 8; r++) { acc[r][0] = p0; acc[r][1] = p1; }
  }

  // ---- segment: nei_v (W1 rows 128..255) ----
  {
    const float* src = h_in + (size_t)(bbase + sidx[sr]) * HH;
    float* dst = seg + sr * SS;
#pragma unroll
    for (int ii = 0; ii < 4; ii++) {
      const int c = (g8 + 8 * ii) * 4;
      *(float4*)(dst + c) = *(const float4*)(src + c);
    }
  }
  __syncthreads();
  gemm_acc(seg, W1 + 128 * HH, c0, r0, acc);

  // ---- segment: nei_s (W1 rows 256..383) ----
  __syncthreads();
  {
    const float* src = hS + (size_t)(bbase + sidx[sr]) * HH;
    float* dst = seg + sr * SS;
#pragma unroll
    for (int ii = 0; ii < 4; ii++) {
      const int c = (g8 + 8 * ii) * 4;
      *(float4*)(dst + c) = *(const float4*)(src + c);
    }
  }
  __syncthreads();
  gemm_acc(seg, W1 + 256 * HH, c0, r0, acc);

  // ---- segment: h_e bf16 (W1 rows 384..511) ----
  __syncthreads();
  {
    const unsigned short* src = he + ((size_t)node * KK + sr) * HH;
    float* dst = seg + sr * SS;
#pragma unroll
    for (int ii = 0; ii < 4; ii++) {
      const int c = (g8 + 8 * ii) * 4;
      const ushort4 u = *(const ushort4*)(src + c);
      float4 f; f.x = bf2f(u.x); f.y = bf2f(u.y); f.z = bf2f(u.z); f.w = bf2f(u.w);
      *(float4*)(dst + c) = f;
    }
  }
  __syncthreads();
  gemm_acc(seg, W1 + 384 * HH, c0, r0, acc);

  // m1 = relu(.) -> mA
#pragma unroll
  for (int r = 0; r < 8; r++) {
    mA[(r0 + r) * SS + c0]      = fmaxf(acc[r][0], 0.f);
    mA[(r0 + r) * SS + c0 + 64] = fmaxf(acc[r][1], 0.f);
    acc[r][0] = 0.f; acc[r][1] = 0.f;
  }
  __syncthreads();

  // m2 = relu(m1 @ W2 + b2) -> seg
  gemm_acc(mA, W2, c0, r0, acc);
  {
    const float b0 = b2[c0], b1v = b2[c0 + 64];
#pragma unroll
    for (int r = 0; r < 8; r++) {
      seg[(r0 + r) * SS + c0]      = fmaxf(acc[r][0] + b0, 0.f);
      seg[(r0 + r) * SS + c0 + 64] = fmaxf(acc[r][1] + b1v, 0.f);
      acc[r][0] = 0.f; acc[r][1] = 0.f;
    }
  }
  __syncthreads();

  // m3 = m2 @ W3 + b3; apply vmask; per-thread partial column sums over 8 rows
  gemm_acc(seg, W3, c0, r0, acc);
  {
    const float b0 = b3[c0], b1v = b3[c0 + 64];
    float s0 = 0.f, s1 = 0.f;
#pragma unroll
    for (int r = 0; r < 8; r++) {
      const float vm = svm[r0 + r];
      s0 += vm * (acc[r][0] + b0);
      s1 += vm * (acc[r][1] + b1v);
    }
    partial[rg * HH + c0]      = s0;
    partial[rg * HH + c0 + 64] = s1;
  }
  __syncthreads();

  // dh = colsum/SCALE; v = h + dh; LayerNorm over 128; * mask
  float v = 0.f;
  if (t < HH) {
    const float dh = (partial[t] + partial[HH + t] + partial[2 * HH + t] + partial[3 * HH + t]) * INV_SCALE;
    v = hc[t] + dh;
  }
  float s = (t < HH) ? v : 0.f;
  float q = (t < HH) ? v * v : 0.f;
#pragma unroll
  for (int off = 32; off >= 1; off >>= 1) { s += __shfl_xor(s, off); q += __shfl_xor(q, off); }
  if ((t & 63) == 0) { redS[t >> 6] = s; redQ[t >> 6] = q; }
  __syncthreads();
  if (t < HH) {
    const float S = redS[0] + redS[1] + redS[2] + redS[3];
    const float Q = redQ[0] + redQ[1] + redQ[2] + redQ[3];
    const float mu  = S * (1.0f / HH);
    const float var = (Q - (float)HH * mu * mu) * (1.0f / (HH - 1));
    const float inv = 1.0f / (sqrtf(var + EPSF) + EPSF);
    const float mc = mask[node];
    h_out[(size_t)node * HH + t] = (gam[t] * (v - mu) * inv + bet[t]) * mc;
  }
}

extern "C" void kernel_launch(void* const* d_in, const int* in_sizes, int n_in,
                              void* d_out, int out_size, void* d_ws, size_t ws_size,
                              hipStream_t stream) {
  const float* V     = (const float*)d_in[0];
  const float* E     = (const float*)d_in[1];
  const float* hS    = (const float*)d_in[2];
  const int*   Eidx  = (const int*)d_in[3];
  const float* mask  = (const float*)d_in[4];
  const float* Wv_w  = (const float*)d_in[5];
  const float* Wv_b  = (const float*)d_in[6];
  const float* Wv_g  = (const float*)d_in[7];
  const float* Wv_be = (const float*)d_in[8];
  const float* We_w  = (const float*)d_in[9];
  const float* We_b  = (const float*)d_in[10];
  const float* We_g  = (const float*)d_in[11];
  const float* We_be = (const float*)d_in[12];
  const float* LW1   = (const float*)d_in[13];
  const float* Lb1   = (const float*)d_in[14];
  const float* LW2   = (const float*)d_in[15];
  const float* Lb2   = (const float*)d_in[16];
  const float* LW3   = (const float*)d_in[17];
  const float* Lb3   = (const float*)d_in[18];
  const float* Lg    = (const float*)d_in[19];
  const float* Lbe   = (const float*)d_in[20];

  // Workspace layout: h_e bf16 [B*N*K*H] (65.5MB), then two f32 h buffers [B*N*H] (4.1MB each)
  unsigned short* he = (unsigned short*)d_ws;
  const size_t heElems = (size_t)BB * NN * KK * HH;
  float* h0 = (float*)((char*)d_ws + heElems * sizeof(unsigned short));
  float* h1 = h0 + (size_t)BB * NN * HH;

  proj_ln_kernel<false><<<dim3((BB * NN) / KK), dim3(256), 0, stream>>>(
      V, Wv_w, Wv_b, Wv_g, Wv_be, (void*)h0);
  proj_ln_kernel<true><<<dim3((BB * NN * KK) / KK), dim3(256), 0, stream>>>(
      E, We_w, We_b, We_g, We_be, (void*)he);

  float* bufs[2] = { h0, h1 };
  const float* hin = bufs[0];
  for (int l = 0; l < 3; l++) {
    float* out = (l == 2) ? (float*)d_out : bufs[(l + 1) & 1];
    layer_step<<<dim3(BB * NN), dim3(256), 0, stream>>>(
        hin, hS, he, Eidx, mask,
        LW1 + (size_t)l * 4 * HH * HH, Lb1 + (size_t)l * HH,
        LW2 + (size_t)l * HH * HH,     Lb2 + (size_t)l * HH,
        LW3 + (size_t)l * HH * HH,     Lb3 + (size_t)l * HH,
        Lg + (size_t)l * HH, Lbe + (size_t)l * HH, out);
    hin = out;
  }
}

// Round 3
// 767.903 us; speedup vs baseline: 2.9122x; 2.9122x over previous
//
#include <hip/hip_runtime.h>
#include <hip/hip_bf16.h>

#define BB 4
#define NN 2000
#define KK 32
#define HH 128
#define DEPTHL 3
constexpr int   SS   = 132;      // padded LDS row stride (floats)
constexpr float EPSF = 1e-6f;
constexpr float INV_SCALE = 1.0f / 30.0f;

typedef __attribute__((ext_vector_type(8))) short bf16x8;   // 8 bf16 in 4 VGPRs
typedef __attribute__((ext_vector_type(4))) float f32x4;

__device__ __forceinline__ float bf2f(unsigned short u) {
  union { unsigned int i; float f; } v; v.i = ((unsigned int)u) << 16; return v.f;
}
__device__ __forceinline__ unsigned short f2bf(float f) {
  union { float f; unsigned int i; } v; v.f = f;
  unsigned int x = v.i;
  return (unsigned short)((x + 0x7FFFu + ((x >> 16) & 1u)) >> 16);
}

// f32 VALU row-GEMM helper (used by small per-node kernels):
// acc[r][c] += sum_i lds[(r0+r)*SS + i] * Wp[i*HH + (c0 + 64*c)]
__device__ __forceinline__ void gemm_acc(const float* __restrict__ lds,
                                         const float* __restrict__ Wp,
                                         int c0, int r0, float acc[8][2]) {
  for (int i = 0; i < HH; i += 4) {
    const float w00 = Wp[(i + 0) * HH + c0], w01 = Wp[(i + 0) * HH + c0 + 64];
    const float w10 = Wp[(i + 1) * HH + c0], w11 = Wp[(i + 1) * HH + c0 + 64];
    const float w20 = Wp[(i + 2) * HH + c0], w21 = Wp[(i + 2) * HH + c0 + 64];
    const float w30 = Wp[(i + 3) * HH + c0], w31 = Wp[(i + 3) * HH + c0 + 64];
#pragma unroll
    for (int r = 0; r < 8; r++) {
      const float4 a = *(const float4*)(lds + (r0 + r) * SS + i);
      acc[r][0] = fmaf(a.w, w30, fmaf(a.z, w20, fmaf(a.y, w10, fmaf(a.x, w00, acc[r][0]))));
      acc[r][1] = fmaf(a.w, w31, fmaf(a.z, w21, fmaf(a.y, w11, fmaf(a.x, w01, acc[r][1]))));
    }
  }
}

// Fused row-projection + LayerNorm (f32 VALU): 32 rows/block, 256 threads.
template <bool OUT_BF16>
__global__ __launch_bounds__(256) void proj_ln_kernel(
    const float* __restrict__ X, const float* __restrict__ W,
    const float* __restrict__ bias, const float* __restrict__ gam,
    const float* __restrict__ bet, void* __restrict__ outp) {
  __shared__ float seg[KK * SS];
  __shared__ float yb[KK * SS];
  const int t = threadIdx.x;
  const size_t row0 = (size_t)blockIdx.x * KK;

  {
    const int r = t >> 3, g8 = t & 7;
    const float* src = X + (row0 + r) * HH;
    float* dst = seg + r * SS;
#pragma unroll
    for (int ii = 0; ii < 4; ii++) {
      const int c = (g8 + 8 * ii) * 4;
      *(float4*)(dst + c) = *(const float4*)(src + c);
    }
  }
  __syncthreads();

  const int c0 = t & 63, rg = t >> 6, r0 = rg * 8;
  float acc[8][2];
  {
    const float b0 = bias[c0], b1v = bias[c0 + 64];
#pragma unroll
    for (int r = 0; r < 8; r++) { acc[r][0] = b0; acc[r][1] = b1v; }
  }
  gemm_acc(seg, W, c0, r0, acc);
#pragma unroll
  for (int r = 0; r < 8; r++) {
    yb[(r0 + r) * SS + c0]      = acc[r][0];
    yb[(r0 + r) * SS + c0 + 64] = acc[r][1];
  }
  __syncthreads();

  const int r = t >> 3, g8 = t & 7;
  float s = 0.f, q = 0.f;
#pragma unroll
  for (int ii = 0; ii < 4; ii++) {
    const int c = (g8 + 8 * ii) * 4;
    const float4 y = *(const float4*)(yb + r * SS + c);
    s += y.x + y.y + y.z + y.w;
    q += y.x * y.x + y.y * y.y + y.z * y.z + y.w * y.w;
  }
  s += __shfl_xor(s, 1); q += __shfl_xor(q, 1);
  s += __shfl_xor(s, 2); q += __shfl_xor(q, 2);
  s += __shfl_xor(s, 4); q += __shfl_xor(q, 4);
  const float mu  = s * (1.0f / HH);
  const float var = (q - (float)HH * mu * mu) * (1.0f / (HH - 1));
  const float inv = 1.0f / (sqrtf(var + EPSF) + EPSF);

#pragma unroll
  for (int ii = 0; ii < 4; ii++) {
    const int c = (g8 + 8 * ii) * 4;
    const float4 y = *(const float4*)(yb + r * SS + c);
    float o0 = gam[c + 0] * (y.x - mu) * inv + bet[c + 0];
    float o1 = gam[c + 1] * (y.y - mu) * inv + bet[c + 1];
    float o2 = gam[c + 2] * (y.z - mu) * inv + bet[c + 2];
    float o3 = gam[c + 3] * (y.w - mu) * inv + bet[c + 3];
    if (OUT_BF16) {
      ushort4 u;
      u.x = f2bf(o0); u.y = f2bf(o1); u.z = f2bf(o2); u.w = f2bf(o3);
      *(ushort4*)((unsigned short*)outp + (row0 + r) * HH + c) = u;
    } else {
      float4 o; o.x = o0; o.y = o1; o.z = o2; o.w = o3;
      *(float4*)((float*)outp + (row0 + r) * HH + c) = o;
    }
  }
}

// Convert + transpose weights to bf16 WT[mat][col][k], mat = l*3 + {W1e, W2, W3}
__global__ __launch_bounds__(256) void wconv_kernel(
    const float* __restrict__ LW1, const float* __restrict__ LW2,
    const float* __restrict__ LW3, unsigned short* __restrict__ WT) {
  const int gid = blockIdx.x * 256 + threadIdx.x;
  const int mat = gid >> 14;
  const int rem = gid & 16383;
  const int col = rem >> 7;
  const int k   = rem & 127;
  const int l = mat / 3, wh = mat % 3;
  float v;
  if (wh == 0)      v = LW1[(size_t)l * 4 * HH * HH + (size_t)(384 + k) * HH + col];
  else if (wh == 1) v = LW2[(size_t)l * HH * HH + (size_t)k * HH + col];
  else              v = LW3[(size_t)l * HH * HH + (size_t)k * HH + col];
  WT[gid] = f2bf(v);
}

// S1[l] = hS @ W1_s[l]  (bf16 out), 32 rows/block, grid = 3*250
__global__ __launch_bounds__(256) void s1_kernel(
    const float* __restrict__ hS, const float* __restrict__ LW1,
    unsigned short* __restrict__ S1) {
  __shared__ float seg[KK * SS];
  const int t = threadIdx.x;
  const int l = blockIdx.x / 250;
  const size_t row0 = (size_t)(blockIdx.x % 250) * KK;
  {
    const int r = t >> 3, g8 = t & 7;
    const float* src = hS + (row0 + r) * HH;
    float* dst = seg + r * SS;
#pragma unroll
    for (int ii = 0; ii < 4; ii++) {
      const int c = (g8 + 8 * ii) * 4;
      *(float4*)(dst + c) = *(const float4*)(src + c);
    }
  }
  __syncthreads();
  const int c0 = t & 63, rg = t >> 6, r0 = rg * 8;
  float acc[8][2];
#pragma unroll
  for (int r = 0; r < 8; r++) { acc[r][0] = 0.f; acc[r][1] = 0.f; }
  gemm_acc(seg, LW1 + (size_t)l * 4 * HH * HH + 256 * HH, c0, r0, acc);
  unsigned short* out = S1 + (size_t)l * BB * NN * HH;
#pragma unroll
  for (int r = 0; r < 8; r++) {
    const size_t gr = (row0 + r0 + r) * HH;
    out[gr + c0]      = f2bf(acc[r][0]);
    out[gr + c0 + 64] = f2bf(acc[r][1]);
  }
}

// Per-layer per-node precompute: C1 = h@W1_c + b1 ; G1 = h@W1_v + S1[l]
__global__ __launch_bounds__(256) void node_pre_kernel(
    const float* __restrict__ h_in, const float* __restrict__ W1,
    const float* __restrict__ b1, const unsigned short* __restrict__ S1l,
    float* __restrict__ C1, float* __restrict__ G1) {
  __shared__ float seg[KK * SS];
  const int t = threadIdx.x;
  const size_t row0 = (size_t)blockIdx.x * KK;
  {
    const int r = t >> 3, g8 = t & 7;
    const float* src = h_in + (row0 + r) * HH;
    float* dst = seg + r * SS;
#pragma unroll
    for (int ii = 0; ii < 4; ii++) {
      const int c = (g8 + 8 * ii) * 4;
      *(float4*)(dst + c) = *(const float4*)(src + c);
    }
  }
  __syncthreads();
  const int c0 = t & 63, rg = t >> 6, r0 = rg * 8;
  float accC[8][2], accG[8][2];
  {
    const float b0 = b1[c0], b1v = b1[c0 + 64];
#pragma unroll
    for (int r = 0; r < 8; r++) {
      accC[r][0] = b0; accC[r][1] = b1v;
      accG[r][0] = 0.f; accG[r][1] = 0.f;
    }
  }
  gemm_acc(seg, W1, c0, r0, accC);                // center quarter (rows 0..127)
  gemm_acc(seg, W1 + 128 * HH, c0, r0, accG);     // nei_v quarter (rows 128..255)
#pragma unroll
  for (int r = 0; r < 8; r++) {
    const size_t gr = (row0 + r0 + r) * HH;
    C1[gr + c0]      = accC[r][0];
    C1[gr + c0 + 64] = accC[r][1];
    G1[gr + c0]      = accG[r][0] + bf2f(S1l[gr + c0]);
    G1[gr + c0 + 64] = accG[r][1] + bf2f(S1l[gr + c0 + 64]);
  }
}

// ---------------- MFMA per-edge kernel: one node per block ----------------
__device__ __forceinline__ bf16x8 ldsA(const unsigned short* T, int rf, int ks, int lr, int lg) {
  const int edge = rf * 16 + lr;
  const int boff = (edge * 256 + ks * 64 + lg * 16) ^ ((edge & 7) << 4);
  return *(const bf16x8*)((const char*)T + boff);
}
__device__ __forceinline__ bf16x8 ldgB(const unsigned short* __restrict__ WT, int col, int ks, int lg) {
  return *(const bf16x8*)(WT + col * 128 + ks * 32 + lg * 8);
}

__global__ __launch_bounds__(256) void edge_kernel(
    const float* __restrict__ h_in, const unsigned short* __restrict__ he,
    const int* __restrict__ E_idx, const float* __restrict__ mask,
    const float* __restrict__ C1, const float* __restrict__ G1,
    const unsigned short* __restrict__ WT1e, const unsigned short* __restrict__ WT2,
    const unsigned short* __restrict__ WT3,
    const float* __restrict__ b2, const float* __restrict__ b3,
    const float* __restrict__ gam, const float* __restrict__ bet,
    float* __restrict__ h_out) {
  __shared__ unsigned short T0[KK * HH];   // bf16 tile, XOR-swizzled
  __shared__ unsigned short T1[KK * HH];
  __shared__ float G1s[KK * SS];
  __shared__ float C1s[HH], hcs[HH], b2s[HH], b3s[HH], dhs[HH];
  __shared__ float svm[KK];
  __shared__ float redS[4], redQ[4];

  const int t = threadIdx.x;
  const int node = blockIdx.x;
  const int bbase = (node / NN) * NN;

  // ---- staging ----
  {
    const int row = t >> 3, cb = (t & 7) * 16;
    const unsigned short* hrow = he + ((size_t)node * KK + row) * HH + cb;
    const bf16x8 e0 = *(const bf16x8*)hrow;
    const bf16x8 e1 = *(const bf16x8*)(hrow + 8);
    const int base = row * 256 + cb * 2;
    const int sw = (row & 7) << 4;
    *(bf16x8*)((char*)T0 + (base ^ sw)) = e0;
    *(bf16x8*)((char*)T0 + ((base + 16) ^ sw)) = e1;
    const int nb = E_idx[(size_t)node * KK + row];
    const float* gsrc = G1 + (size_t)(bbase + nb) * HH + cb;
    float* gdst = G1s + row * SS + cb;
#pragma unroll
    for (int ii = 0; ii < 4; ii++) *(float4*)(gdst + ii * 4) = *(const float4*)(gsrc + ii * 4);
  }
  if (t < HH) { C1s[t] = C1[(size_t)node * HH + t]; hcs[t] = h_in[(size_t)node * HH + t]; }
  else        { b2s[t - HH] = b2[t - HH]; b3s[t - HH] = b3[t - HH]; }
  if (t < KK) svm[t] = mask[bbase + E_idx[(size_t)node * KK + t]];
  __syncthreads();

  const int lane = t & 63, wid = t >> 6;
  const int lr = lane & 15, lg = lane >> 4;
  const int colbase = wid * 32;
  const int col0 = colbase + lr, col1 = colbase + 16 + lr;

  f32x4 a00, a01, a10, a11;

#define ZERO_ACC() do { a00 = (f32x4){0.f,0.f,0.f,0.f}; a01 = a00; a10 = a00; a11 = a00; } while (0)
#define DO_GEMM(TILE, WTm) do {                                            \
    _Pragma("unroll")                                                      \
    for (int ks = 0; ks < 4; ks++) {                                       \
      const bf16x8 fa0 = ldsA(TILE, 0, ks, lr, lg);                        \
      const bf16x8 fa1 = ldsA(TILE, 1, ks, lr, lg);                        \
      const bf16x8 fb0 = ldgB(WTm, col0, ks, lg);                          \
      const bf16x8 fb1 = ldgB(WTm, col1, ks, lg);                          \
      a00 = __builtin_amdgcn_mfma_f32_16x16x32_bf16(fa0, fb0, a00, 0, 0, 0); \
      a01 = __builtin_amdgcn_mfma_f32_16x16x32_bf16(fa0, fb1, a01, 0, 0, 0); \
      a10 = __builtin_amdgcn_mfma_f32_16x16x32_bf16(fa1, fb0, a10, 0, 0, 0); \
      a11 = __builtin_amdgcn_mfma_f32_16x16x32_bf16(fa1, fb1, a11, 0, 0, 0); \
    } } while (0)

  // ---- GEMM1: m1 = relu(he @ W1e + C1 + gather(G1)) ----
  ZERO_ACC();
  DO_GEMM(T0, WT1e);
  {
    const float c0a = C1s[col0], c1a = C1s[col1];
#pragma unroll
    for (int rf = 0; rf < 2; rf++) {
      const f32x4 v0 = rf ? a10 : a00;
      const f32x4 v1 = rf ? a11 : a01;
#pragma unroll
      for (int r = 0; r < 4; r++) {
        const int edge = rf * 16 + lg * 4 + r;
        const int sw = (edge & 7) << 4;
        const float x0 = fmaxf(v0[r] + c0a + G1s[edge * SS + col0], 0.f);
        const float x1 = fmaxf(v1[r] + c1a + G1s[edge * SS + col1], 0.f);
        *(unsigned short*)((char*)T1 + ((edge * 256 + col0 * 2) ^ sw)) = f2bf(x0);
        *(unsigned short*)((char*)T1 + ((edge * 256 + col1 * 2) ^ sw)) = f2bf(x1);
      }
    }
  }
  __syncthreads();

  // ---- GEMM2: m2 = relu(m1 @ W2 + b2) ----
  ZERO_ACC();
  DO_GEMM(T1, WT2);
  {
    const float c0a = b2s[col0], c1a = b2s[col1];
#pragma unroll
    for (int rf = 0; rf < 2; rf++) {
      const f32x4 v0 = rf ? a10 : a00;
      const f32x4 v1 = rf ? a11 : a01;
#pragma unroll
      for (int r = 0; r < 4; r++) {
        const int edge = rf * 16 + lg * 4 + r;
        const int sw = (edge & 7) << 4;
        const float x0 = fmaxf(v0[r] + c0a, 0.f);
        const float x1 = fmaxf(v1[r] + c1a, 0.f);
        *(unsigned short*)((char*)T0 + ((edge * 256 + col0 * 2) ^ sw)) = f2bf(x0);
        *(unsigned short*)((char*)T0 + ((edge * 256 + col1 * 2) ^ sw)) = f2bf(x1);
      }
    }
  }
  __syncthreads();

  // ---- GEMM3: m3 = m2 @ W3 + b3; mask; column-sum over edges ----
  ZERO_ACC();
  DO_GEMM(T0, WT3);
  {
    const float cb0 = b3s[col0], cb1 = b3s[col1];
    float s0 = 0.f, s1 = 0.f;
#pragma unroll
    for (int rf = 0; rf < 2; rf++) {
      const f32x4 v0 = rf ? a10 : a00;
      const f32x4 v1 = rf ? a11 : a01;
#pragma unroll
      for (int r = 0; r < 4; r++) {
        const int edge = rf * 16 + lg * 4 + r;
        const float vm = svm[edge];
        s0 += vm * (v0[r] + cb0);
        s1 += vm * (v1[r] + cb1);
      }
    }
    s0 += __shfl_xor(s0, 16); s0 += __shfl_xor(s0, 32);
    s1 += __shfl_xor(s1, 16); s1 += __shfl_xor(s1, 32);
    if (lg == 0) { dhs[col0] = s0; dhs[col1] = s1; }
  }
  __syncthreads();

  // ---- residual + LayerNorm + mask ----
  float v = 0.f;
  if (t < HH) v = hcs[t] + dhs[t] * INV_SCALE;
  float s = (t < HH) ? v : 0.f;
  float q = (t < HH) ? v * v : 0.f;
#pragma unroll
  for (int off = 32; off >= 1; off >>= 1) { s += __shfl_xor(s, off); q += __shfl_xor(q, off); }
  if ((t & 63) == 0) { redS[t >> 6] = s; redQ[t >> 6] = q; }
  __syncthreads();
  if (t < HH) {
    const float S = redS[0] + redS[1] + redS[2] + redS[3];
    const float Q = redQ[0] + redQ[1] + redQ[2] + redQ[3];
    const float mu  = S * (1.0f / HH);
    const float var = (Q - (float)HH * mu * mu) * (1.0f / (HH - 1));
    const float inv = 1.0f / (sqrtf(var + EPSF) + EPSF);
    h_out[(size_t)node * HH + t] = (gam[t] * (v - mu) * inv + bet[t]) * mask[node];
  }
#undef ZERO_ACC
#undef DO_GEMM
}

extern "C" void kernel_launch(void* const* d_in, const int* in_sizes, int n_in,
                              void* d_out, int out_size, void* d_ws, size_t ws_size,
                              hipStream_t stream) {
  const float* V     = (const float*)d_in[0];
  const float* E     = (const float*)d_in[1];
  const float* hS    = (const float*)d_in[2];
  const int*   Eidx  = (const int*)d_in[3];
  const float* mask  = (const float*)d_in[4];
  const float* Wv_w  = (const float*)d_in[5];
  const float* Wv_b  = (const float*)d_in[6];
  const float* Wv_g  = (const float*)d_in[7];
  const float* Wv_be = (const float*)d_in[8];
  const float* We_w  = (const float*)d_in[9];
  const float* We_b  = (const float*)d_in[10];
  const float* We_g  = (const float*)d_in[11];
  const float* We_be = (const float*)d_in[12];
  const float* LW1   = (const float*)d_in[13];
  const float* Lb1   = (const float*)d_in[14];
  const float* LW2   = (const float*)d_in[15];
  const float* Lb2   = (const float*)d_in[16];
  const float* LW3   = (const float*)d_in[17];
  const float* Lb3   = (const float*)d_in[18];
  const float* Lg    = (const float*)d_in[19];
  const float* Lbe   = (const float*)d_in[20];

  // ---- workspace layout (bytes) ----
  char* w = (char*)d_ws;
  unsigned short* he  = (unsigned short*)(w);                    // 65,536,000
  unsigned short* S1  = (unsigned short*)(w + 65536000);         //  6,144,000
  float* C1           = (float*)(w + 71680000);                  //  4,096,000
  float* G1           = (float*)(w + 75776000);                  //  4,096,000
  unsigned short* WT  = (unsigned short*)(w + 79872000);         //    294,912
  float* h0           = (float*)(w + 80166912);                  //  4,096,000
  float* h1           = (float*)(w + 84262912);                  //  4,096,000

  wconv_kernel<<<dim3(576), dim3(256), 0, stream>>>(LW1, LW2, LW3, WT);
  s1_kernel<<<dim3(750), dim3(256), 0, stream>>>(hS, LW1, S1);
  proj_ln_kernel<false><<<dim3((BB * NN) / KK), dim3(256), 0, stream>>>(
      V, Wv_w, Wv_b, Wv_g, Wv_be, (void*)h0);
  proj_ln_kernel<true><<<dim3((BB * NN * KK) / KK), dim3(256), 0, stream>>>(
      E, We_w, We_b, We_g, We_be, (void*)he);

  const float* hin = h0;
  float* bufs[2] = { h1, h0 };
  for (int l = 0; l < DEPTHL; l++) {
    node_pre_kernel<<<dim3(250), dim3(256), 0, stream>>>(
        hin, LW1 + (size_t)l * 4 * HH * HH, Lb1 + (size_t)l * HH,
        S1 + (size_t)l * BB * NN * HH, C1, G1);
    float* out = (l == DEPTHL - 1) ? (float*)d_out : bufs[l & 1];
    edge_kernel<<<dim3(BB * NN), dim3(256), 0, stream>>>(
        hin, he, Eidx, mask, C1, G1,
        WT + (size_t)(l * 3 + 0) * HH * HH,
        WT + (size_t)(l * 3 + 1) * HH * HH,
        WT + (size_t)(l * 3 + 2) * HH * HH,
        Lb2 + (size_t)l * HH, Lb3 + (size_t)l * HH,
        Lg + (size_t)l * HH, Lbe + (size_t)l * HH, out);
    hin = out;
  }
}

// Round 7
// 699.505 us; speedup vs baseline: 3.1970x; 1.0978x over previous
//
#include <hip/hip_runtime.h>
#include <hip/hip_bf16.h>

#define BB 4
#define NN 2000
#define KK 32
#define HH 128
#define DEPTHL 3
constexpr int   SS   = 132;      // padded LDS row stride (floats)
constexpr float EPSF = 1e-6f;
constexpr float INV_SCALE = 1.0f / 30.0f;

typedef __attribute__((ext_vector_type(8))) short bf16x8;   // 8 bf16 in 4 VGPRs
typedef __attribute__((ext_vector_type(4))) short bf16x4;   // 8 bytes
typedef __attribute__((ext_vector_type(4))) float f32x4;

__device__ __forceinline__ float bf2f(unsigned short u) {
  union { unsigned int i; float f; } v; v.i = ((unsigned int)u) << 16; return v.f;
}
__device__ __forceinline__ unsigned short f2bf(float f) {
  union { float f; unsigned int i; } v; v.f = f;
  unsigned int x = v.i;
  return (unsigned short)((x + 0x7FFFu + ((x >> 16) & 1u)) >> 16);
}

// f32 VALU row-GEMM helper (small per-node kernels)
__device__ __forceinline__ void gemm_acc(const float* __restrict__ lds,
                                         const float* __restrict__ Wp,
                                         int c0, int r0, float acc[8][2]) {
  for (int i = 0; i < HH; i += 4) {
    const float w00 = Wp[(i + 0) * HH + c0], w01 = Wp[(i + 0) * HH + c0 + 64];
    const float w10 = Wp[(i + 1) * HH + c0], w11 = Wp[(i + 1) * HH + c0 + 64];
    const float w20 = Wp[(i + 2) * HH + c0], w21 = Wp[(i + 2) * HH + c0 + 64];
    const float w30 = Wp[(i + 3) * HH + c0], w31 = Wp[(i + 3) * HH + c0 + 64];
#pragma unroll
    for (int r = 0; r < 8; r++) {
      const float4 a = *(const float4*)(lds + (r0 + r) * SS + i);
      acc[r][0] = fmaf(a.w, w30, fmaf(a.z, w20, fmaf(a.y, w10, fmaf(a.x, w00, acc[r][0]))));
      acc[r][1] = fmaf(a.w, w31, fmaf(a.z, w21, fmaf(a.y, w11, fmaf(a.x, w01, acc[r][1]))));
    }
  }
}

// Fused row-projection + LayerNorm (f32 VALU) — V path only now.
template <bool OUT_BF16>
__global__ __launch_bounds__(256) void proj_ln_kernel(
    const float* __restrict__ X, const float* __restrict__ W,
    const float* __restrict__ bias, const float* __restrict__ gam,
    const float* __restrict__ bet, void* __restrict__ outp) {
  __shared__ float seg[KK * SS];
  __shared__ float yb[KK * SS];
  const int t = threadIdx.x;
  const size_t row0 = (size_t)blockIdx.x * KK;

  {
    const int r = t >> 3, g8 = t & 7;
    const float* src = X + (row0 + r) * HH;
    float* dst = seg + r * SS;
#pragma unroll
    for (int ii = 0; ii < 4; ii++) {
      const int c = (g8 + 8 * ii) * 4;
      *(float4*)(dst + c) = *(const float4*)(src + c);
    }
  }
  __syncthreads();

  const int c0 = t & 63, rg = t >> 6, r0 = rg * 8;
  float acc[8][2];
  {
    const float b0 = bias[c0], b1v = bias[c0 + 64];
#pragma unroll
    for (int r = 0; r < 8; r++) { acc[r][0] = b0; acc[r][1] = b1v; }
  }
  gemm_acc(seg, W, c0, r0, acc);
#pragma unroll
  for (int r = 0; r < 8; r++) {
    yb[(r0 + r) * SS + c0]      = acc[r][0];
    yb[(r0 + r) * SS + c0 + 64] = acc[r][1];
  }
  __syncthreads();

  const int r = t >> 3, g8 = t & 7;
  float s = 0.f, q = 0.f;
#pragma unroll
  for (int ii = 0; ii < 4; ii++) {
    const int c = (g8 + 8 * ii) * 4;
    const float4 y = *(const float4*)(yb + r * SS + c);
    s += y.x + y.y + y.z + y.w;
    q += y.x * y.x + y.y * y.y + y.z * y.z + y.w * y.w;
  }
  s += __shfl_xor(s, 1); q += __shfl_xor(q, 1);
  s += __shfl_xor(s, 2); q += __shfl_xor(q, 2);
  s += __shfl_xor(s, 4); q += __shfl_xor(q, 4);
  const float mu  = s * (1.0f / HH);
  const float var = (q - (float)HH * mu * mu) * (1.0f / (HH - 1));
  const float inv = 1.0f / (sqrtf(var + EPSF) + EPSF);

#pragma unroll
  for (int ii = 0; ii < 4; ii++) {
    const int c = (g8 + 8 * ii) * 4;
    const float4 y = *(const float4*)(yb + r * SS + c);
    float o0 = gam[c + 0] * (y.x - mu) * inv + bet[c + 0];
    float o1 = gam[c + 1] * (y.y - mu) * inv + bet[c + 1];
    float o2 = gam[c + 2] * (y.z - mu) * inv + bet[c + 2];
    float o3 = gam[c + 3] * (y.w - mu) * inv + bet[c + 3];
    if (OUT_BF16) {
      ushort4 u;
      u.x = f2bf(o0); u.y = f2bf(o1); u.z = f2bf(o2); u.w = f2bf(o3);
      *(ushort4*)((unsigned short*)outp + (row0 + r) * HH + c) = u;
    } else {
      float4 o; o.x = o0; o.y = o1; o.z = o2; o.w = o3;
      *(float4*)((float*)outp + (row0 + r) * HH + c) = o;
    }
  }
}

// Convert + transpose weights to bf16 WT[mat][col][k]:
// mat 0..8 = l*3 + {W1e, W2, W3}; mat 9 = We_w^T
__global__ __launch_bounds__(256) void wconv_kernel(
    const float* __restrict__ LW1, const float* __restrict__ LW2,
    const float* __restrict__ LW3, const float* __restrict__ Wew,
    unsigned short* __restrict__ WT) {
  const int gid = blockIdx.x * 256 + threadIdx.x;
  const int mat = gid >> 14;
  const int rem = gid & 16383;
  const int col = rem >> 7;
  const int k   = rem & 127;
  float v;
  if (mat == 9) {
    v = Wew[(size_t)k * HH + col];
  } else {
    const int l = mat / 3, wh = mat % 3;
    if (wh == 0)      v = LW1[(size_t)l * 4 * HH * HH + (size_t)(384 + k) * HH + col];
    else if (wh == 1) v = LW2[(size_t)l * HH * HH + (size_t)k * HH + col];
    else              v = LW3[(size_t)l * HH * HH + (size_t)k * HH + col];
  }
  WT[gid] = f2bf(v);
}

// S1[l] = hS @ W1_s[l]  (bf16 out)
__global__ __launch_bounds__(256) void s1_kernel(
    const float* __restrict__ hS, const float* __restrict__ LW1,
    unsigned short* __restrict__ S1) {
  __shared__ float seg[KK * SS];
  const int t = threadIdx.x;
  const int l = blockIdx.x / 250;
  const size_t row0 = (size_t)(blockIdx.x % 250) * KK;
  {
    const int r = t >> 3, g8 = t & 7;
    const float* src = hS + (row0 + r) * HH;
    float* dst = seg + r * SS;
#pragma unroll
    for (int ii = 0; ii < 4; ii++) {
      const int c = (g8 + 8 * ii) * 4;
      *(float4*)(dst + c) = *(const float4*)(src + c);
    }
  }
  __syncthreads();
  const int c0 = t & 63, rg = t >> 6, r0 = rg * 8;
  float acc[8][2];
#pragma unroll
  for (int r = 0; r < 8; r++) { acc[r][0] = 0.f; acc[r][1] = 0.f; }
  gemm_acc(seg, LW1 + (size_t)l * 4 * HH * HH + 256 * HH, c0, r0, acc);
  unsigned short* out = S1 + (size_t)l * BB * NN * HH;
#pragma unroll
  for (int r = 0; r < 8; r++) {
    const size_t gr = (row0 + r0 + r) * HH;
    out[gr + c0]      = f2bf(acc[r][0]);
    out[gr + c0 + 64] = f2bf(acc[r][1]);
  }
}

// Per-layer per-node precompute: C1 = h@W1_c + b1 (f32); G1 = h@W1_v + S1[l] (bf16)
__global__ __launch_bounds__(256) void node_pre_kernel(
    const float* __restrict__ h_in, const float* __restrict__ W1,
    const float* __restrict__ b1, const unsigned short* __restrict__ S1l,
    float* __restrict__ C1, unsigned short* __restrict__ G1) {
  __shared__ float seg[KK * SS];
  const int t = threadIdx.x;
  const size_t row0 = (size_t)blockIdx.x * KK;
  {
    const int r = t >> 3, g8 = t & 7;
    const float* src = h_in + (row0 + r) * HH;
    float* dst = seg + r * SS;
#pragma unroll
    for (int ii = 0; ii < 4; ii++) {
      const int c = (g8 + 8 * ii) * 4;
      *(float4*)(dst + c) = *(const float4*)(src + c);
    }
  }
  __syncthreads();
  const int c0 = t & 63, rg = t >> 6, r0 = rg * 8;
  float accC[8][2], accG[8][2];
  {
    const float b0 = b1[c0], b1v = b1[c0 + 64];
#pragma unroll
    for (int r = 0; r < 8; r++) {
      accC[r][0] = b0; accC[r][1] = b1v;
      accG[r][0] = 0.f; accG[r][1] = 0.f;
    }
  }
  gemm_acc(seg, W1, c0, r0, accC);                // center quarter
  gemm_acc(seg, W1 + 128 * HH, c0, r0, accG);     // nei_v quarter
#pragma unroll
  for (int r = 0; r < 8; r++) {
    const size_t gr = (row0 + r0 + r) * HH;
    C1[gr + c0]      = accC[r][0];
    C1[gr + c0 + 64] = accC[r][1];
    G1[gr + c0]      = f2bf(accG[r][0] + bf2f(S1l[gr + c0]));
    G1[gr + c0 + 64] = f2bf(accG[r][1] + bf2f(S1l[gr + c0 + 64]));
  }
}

// ---- MFMA fragment loaders (shared by E-projection and edge kernel) ----
// A/B fragment from swizzled LDS tile [32 rows][128 cols] bf16:
// returns tile[row = rf*16+lr][k = ks*32 + lg*8 .. +8]
__device__ __forceinline__ bf16x8 ldsA(const unsigned short* T, int rf, int ks, int lr, int lg) {
  const int row = rf * 16 + lr;
  const int boff = (row * 256 + ks * 64 + lg * 16) ^ ((row & 7) << 4);
  return *(const bf16x8*)((const char*)T + boff);
}
// fragment from global WT[col][k] (k contiguous)
__device__ __forceinline__ bf16x8 ldgB(const unsigned short* __restrict__ WT, int col, int ks, int lg) {
  return *(const bf16x8*)(WT + col * 128 + ks * 32 + lg * 8);
}

// ---------- MFMA E-projection + LayerNorm: 32 rows/block ----------
__global__ __launch_bounds__(256) void proj_ln_e_mfma(
    const float* __restrict__ E, const unsigned short* __restrict__ WeT,
    const float* __restrict__ bias, const float* __restrict__ gam,
    const float* __restrict__ bet, unsigned short* __restrict__ he) {
  __shared__ unsigned short T0[KK * HH];
  __shared__ float yb[KK * SS];
  __shared__ float biasS[HH];
  const int t = threadIdx.x;
  const size_t row0 = (size_t)blockIdx.x * KK;

  {
    const int row = t >> 3, cb = (t & 7) * 16;
    const float* src = E + (row0 + row) * HH + cb;
    const float4 f0 = *(const float4*)(src);
    const float4 f1 = *(const float4*)(src + 4);
    const float4 f2 = *(const float4*)(src + 8);
    const float4 f3 = *(const float4*)(src + 12);
    bf16x8 u0, u1;
    u0[0] = (short)f2bf(f0.x); u0[1] = (short)f2bf(f0.y); u0[2] = (short)f2bf(f0.z); u0[3] = (short)f2bf(f0.w);
    u0[4] = (short)f2bf(f1.x); u0[5] = (short)f2bf(f1.y); u0[6] = (short)f2bf(f1.z); u0[7] = (short)f2bf(f1.w);
    u1[0] = (short)f2bf(f2.x); u1[1] = (short)f2bf(f2.y); u1[2] = (short)f2bf(f2.z); u1[3] = (short)f2bf(f2.w);
    u1[4] = (short)f2bf(f3.x); u1[5] = (short)f2bf(f3.y); u1[6] = (short)f2bf(f3.z); u1[7] = (short)f2bf(f3.w);
    const int base = row * 256 + cb * 2;
    const int sw = (row & 7) << 4;
    *(bf16x8*)((char*)T0 + (base ^ sw)) = u0;
    *(bf16x8*)((char*)T0 + ((base + 16) ^ sw)) = u1;
  }
  if (t < HH) biasS[t] = bias[t];
  __syncthreads();

  const int lane = t & 63, wid = t >> 6, lr = lane & 15, lg = lane >> 4;
  const int wbase = wid * 32;
  f32x4 a00 = (f32x4){0.f,0.f,0.f,0.f}, a01 = a00, a10 = a00, a11 = a00;
#pragma unroll
  for (int ks = 0; ks < 4; ks++) {
    const bf16x8 fw0 = ldgB(WeT, wbase + lr, ks, lg);
    const bf16x8 fw1 = ldgB(WeT, wbase + 16 + lr, ks, lg);
    const bf16x8 ft0 = ldsA(T0, 0, ks, lr, lg);
    const bf16x8 ft1 = ldsA(T0, 1, ks, lr, lg);
    a00 = __builtin_amdgcn_mfma_f32_16x16x32_bf16(fw0, ft0, a00, 0, 0, 0);
    a01 = __builtin_amdgcn_mfma_f32_16x16x32_bf16(fw0, ft1, a01, 0, 0, 0);
    a10 = __builtin_amdgcn_mfma_f32_16x16x32_bf16(fw1, ft0, a10, 0, 0, 0);
    a11 = __builtin_amdgcn_mfma_f32_16x16x32_bf16(fw1, ft1, a11, 0, 0, 0);
  }
  // D = [outcol x edge]; lane holds edge = b*16+lr, outcols col0..col0+3
#pragma unroll
  for (int a = 0; a < 2; a++) {
    const int col0 = wbase + a * 16 + lg * 4;
    const float4 bv = *(const float4*)(biasS + col0);
#pragma unroll
    for (int b = 0; b < 2; b++) {
      const int edge = b * 16 + lr;
      const f32x4 ac = a == 0 ? (b == 0 ? a00 : a01) : (b == 0 ? a10 : a11);
      float4 y; y.x = ac[0] + bv.x; y.y = ac[1] + bv.y; y.z = ac[2] + bv.z; y.w = ac[3] + bv.w;
      *(float4*)(yb + edge * SS + col0) = y;
    }
  }
  __syncthreads();

  const int r = t >> 3, g8 = t & 7;
  float s = 0.f, q = 0.f;
#pragma unroll
  for (int ii = 0; ii < 4; ii++) {
    const int c = (g8 + 8 * ii) * 4;
    const float4 y = *(const float4*)(yb + r * SS + c);
    s += y.x + y.y + y.z + y.w;
    q += y.x * y.x + y.y * y.y + y.z * y.z + y.w * y.w;
  }
  s += __shfl_xor(s, 1); q += __shfl_xor(q, 1);
  s += __shfl_xor(s, 2); q += __shfl_xor(q, 2);
  s += __shfl_xor(s, 4); q += __shfl_xor(q, 4);
  const float mu  = s * (1.0f / HH);
  const float var = (q - (float)HH * mu * mu) * (1.0f / (HH - 1));
  const float inv = 1.0f / (sqrtf(var + EPSF) + EPSF);
#pragma unroll
  for (int ii = 0; ii < 4; ii++) {
    const int c = (g8 + 8 * ii) * 4;
    const float4 y = *(const float4*)(yb + r * SS + c);
    ushort4 u;
    u.x = f2bf(gam[c + 0] * (y.x - mu) * inv + bet[c + 0]);
    u.y = f2bf(gam[c + 1] * (y.y - mu) * inv + bet[c + 1]);
    u.z = f2bf(gam[c + 2] * (y.z - mu) * inv + bet[c + 2]);
    u.w = f2bf(gam[c + 3] * (y.w - mu) * inv + bet[c + 3]);
    *(ushort4*)(he + (row0 + r) * HH + c) = u;
  }
}

// ---------------- MFMA per-edge kernel: TWO nodes per block ----------------
__global__ __launch_bounds__(512, 6) void edge_kernel(
    const float* __restrict__ h_in, const unsigned short* __restrict__ he,
    const int* __restrict__ E_idx, const float* __restrict__ mask,
    const float* __restrict__ C1, const unsigned short* __restrict__ G1,
    const unsigned short* __restrict__ WT1e, const unsigned short* __restrict__ WT2,
    const unsigned short* __restrict__ WT3,
    const float* __restrict__ b2, const float* __restrict__ b3,
    const float* __restrict__ gam, const float* __restrict__ bet,
    float* __restrict__ h_out) {
  __shared__ unsigned short T0[2][KK * HH];   // bf16 tiles, XOR-swizzled
  __shared__ unsigned short T1[2][KK * HH];
  __shared__ unsigned short G1s[2][KK * HH];
  __shared__ float C1s[2][HH], dhs[2][HH];
  __shared__ float b2s[HH], b3s[HH];
  __shared__ float svm[2][KK];
  __shared__ float redS[2][4], redQ[2][4];

  const int t = threadIdx.x;
  const int nh = t >> 8, tt = t & 255;
  const int node = blockIdx.x * 2 + nh;
  const int bbase = (node / NN) * NN;

  // ---- staging ----
  {
    const int row = tt >> 3, cb = (tt & 7) * 16;
    const unsigned short* hrow = he + ((size_t)node * KK + row) * HH + cb;
    const bf16x8 e0 = *(const bf16x8*)hrow;
    const bf16x8 e1 = *(const bf16x8*)(hrow + 8);
    const int base = row * 256 + cb * 2;
    const int sw = (row & 7) << 4;
    *(bf16x8*)((char*)T0[nh] + (base ^ sw)) = e0;
    *(bf16x8*)((char*)T0[nh] + ((base + 16) ^ sw)) = e1;
    const int nb = E_idx[(size_t)node * KK + row];
    const unsigned short* gsrc = G1 + (size_t)(bbase + nb) * HH + cb;
    const bf16x8 g0 = *(const bf16x8*)gsrc;
    const bf16x8 g1 = *(const bf16x8*)(gsrc + 8);
    *(bf16x8*)((char*)G1s[nh] + (base ^ sw)) = g0;
    *(bf16x8*)((char*)G1s[nh] + ((base + 16) ^ sw)) = g1;
  }
  if (tt < HH) C1s[nh][tt] = C1[(size_t)node * HH + tt];
  if (t < HH) b2s[t] = b2[t];
  else if (t < 2 * HH) b3s[t - HH] = b3[t - HH];
  if (tt < KK) svm[nh][tt] = mask[bbase + E_idx[(size_t)node * KK + tt]];
  __syncthreads();

  const int lane = tt & 63, wid = tt >> 6, lr = lane & 15, lg = lane >> 4;
  const int wbase = wid * 32;
  f32x4 a00, a01, a10, a11;

#define ZERO_ACC() do { a00 = (f32x4){0.f,0.f,0.f,0.f}; a01 = a00; a10 = a00; a11 = a00; } while (0)
// Transposed form: A = weight frags (rows = outcols), B = tile frags (cols = edges)
#define DO_GEMM_T(TILE, WTm) do {                                          \
    _Pragma("unroll")                                                      \
    for (int ks = 0; ks < 4; ks++) {                                       \
      const bf16x8 fw0 = ldgB(WTm, wbase + lr, ks, lg);                    \
      const bf16x8 fw1 = ldgB(WTm, wbase + 16 + lr, ks, lg);               \
      const bf16x8 ft0 = ldsA(TILE, 0, ks, lr, lg);                        \
      const bf16x8 ft1 = ldsA(TILE, 1, ks, lr, lg);                        \
      a00 = __builtin_amdgcn_mfma_f32_16x16x32_bf16(fw0, ft0, a00, 0, 0, 0); \
      a01 = __builtin_amdgcn_mfma_f32_16x16x32_bf16(fw0, ft1, a01, 0, 0, 0); \
      a10 = __builtin_amdgcn_mfma_f32_16x16x32_bf16(fw1, ft0, a10, 0, 0, 0); \
      a11 = __builtin_amdgcn_mfma_f32_16x16x32_bf16(fw1, ft1, a11, 0, 0, 0); \
    } } while (0)

  // ---- GEMM1 (transposed): m1 = relu(he @ W1e + C1 + G1gather) -> T1 ----
  ZERO_ACC();
  DO_GEMM_T(T0[nh], WT1e);
#pragma unroll
  for (int a = 0; a < 2; a++) {
    const int col0 = wbase + a * 16 + lg * 4;
    const float4 c1v = *(const float4*)(&C1s[nh][col0]);
#pragma unroll
    for (int b = 0; b < 2; b++) {
      const int edge = b * 16 + lr;
      const int boff = (edge * 256 + col0 * 2) ^ ((edge & 7) << 4);
      const bf16x4 g = *(const bf16x4*)((const char*)G1s[nh] + boff);
      const f32x4 ac = a == 0 ? (b == 0 ? a00 : a01) : (b == 0 ? a10 : a11);
      const float x0 = fmaxf(ac[0] + c1v.x + bf2f((unsigned short)g[0]), 0.f);
      const float x1 = fmaxf(ac[1] + c1v.y + bf2f((unsigned short)g[1]), 0.f);
      const float x2 = fmaxf(ac[2] + c1v.z + bf2f((unsigned short)g[2]), 0.f);
      const float x3 = fmaxf(ac[3] + c1v.w + bf2f((unsigned short)g[3]), 0.f);
      uint2 pv;
      pv.x = (unsigned)f2bf(x0) | ((unsigned)f2bf(x1) << 16);
      pv.y = (unsigned)f2bf(x2) | ((unsigned)f2bf(x3) << 16);
      *(uint2*)((char*)T1[nh] + boff) = pv;
    }
  }
  __syncthreads();

  // ---- GEMM2 (transposed): m2 = relu(m1 @ W2 + b2) -> T0 ----
  ZERO_ACC();
  DO_GEMM_T(T1[nh], WT2);
#pragma unroll
  for (int a = 0; a < 2; a++) {
    const int col0 = wbase + a * 16 + lg * 4;
    const float4 bv = *(const float4*)(b2s + col0);
#pragma unroll
    for (int b = 0; b < 2; b++) {
      const int edge = b * 16 + lr;
      const int boff = (edge * 256 + col0 * 2) ^ ((edge & 7) << 4);
      const f32x4 ac = a == 0 ? (b == 0 ? a00 : a01) : (b == 0 ? a10 : a11);
      const float x0 = fmaxf(ac[0] + bv.x, 0.f);
      const float x1 = fmaxf(ac[1] + bv.y, 0.f);
      const float x2 = fmaxf(ac[2] + bv.z, 0.f);
      const float x3 = fmaxf(ac[3] + bv.w, 0.f);
      uint2 pv;
      pv.x = (unsigned)f2bf(x0) | ((unsigned)f2bf(x1) << 16);
      pv.y = (unsigned)f2bf(x2) | ((unsigned)f2bf(x3) << 16);
      *(uint2*)((char*)T0[nh] + boff) = pv;
    }
  }
  __syncthreads();

  // ---- GEMM3 (original form): m3 = m2 @ W3 + b3; mask; column-sum over edges ----
  ZERO_ACC();
  {
    const int col0 = wbase + lr, col1 = wbase + 16 + lr;
#pragma unroll
    for (int ks = 0; ks < 4; ks++) {
      const bf16x8 fa0 = ldsA(T0[nh], 0, ks, lr, lg);
      const bf16x8 fa1 = ldsA(T0[nh], 1, ks, lr, lg);
      const bf16x8 fb0 = ldgB(WT3, col0, ks, lg);
      const bf16x8 fb1 = ldgB(WT3, col1, ks, lg);
      a00 = __builtin_amdgcn_mfma_f32_16x16x32_bf16(fa0, fb0, a00, 0, 0, 0);
      a01 = __builtin_amdgcn_mfma_f32_16x16x32_bf16(fa0, fb1, a01, 0, 0, 0);
      a10 = __builtin_amdgcn_mfma_f32_16x16x32_bf16(fa1, fb0, a10, 0, 0, 0);
      a11 = __builtin_amdgcn_mfma_f32_16x16x32_bf16(fa1, fb1, a11, 0, 0, 0);
    }
    const float cb0 = b3s[col0], cb1 = b3s[col1];
    float s0 = 0.f, s1 = 0.f;
#pragma unroll
    for (int rf = 0; rf < 2; rf++) {
      const f32x4 v0 = rf ? a10 : a00;
      const f32x4 v1 = rf ? a11 : a01;
#pragma unroll
      for (int r = 0; r < 4; r++) {
        const int edge = rf * 16 + lg * 4 + r;
        const float vm = svm[nh][edge];
        s0 += vm * (v0[r] + cb0);
        s1 += vm * (v1[r] + cb1);
      }
    }
    s0 += __shfl_xor(s0, 16); s0 += __shfl_xor(s0, 32);
    s1 += __shfl_xor(s1, 16); s1 += __shfl_xor(s1, 32);
    if (lg == 0) { dhs[nh][col0] = s0; dhs[nh][col1] = s1; }
  }
  __syncthreads();

  // ---- residual + LayerNorm + mask ----
  float v = 0.f;
  if (tt < HH) v = h_in[(size_t)node * HH + tt] + dhs[nh][tt] * INV_SCALE;
  float s = (tt < HH) ? v : 0.f;
  float q = (tt < HH) ? v * v : 0.f;
#pragma unroll
  for (int off = 32; off >= 1; off >>= 1) { s += __shfl_xor(s, off); q += __shfl_xor(q, off); }
  if ((tt & 63) == 0) { redS[nh][tt >> 6] = s; redQ[nh][tt >> 6] = q; }
  __syncthreads();
  if (tt < HH) {
    const float S = redS[nh][0] + redS[nh][1] + redS[nh][2] + redS[nh][3];
    const float Q = redQ[nh][0] + redQ[nh][1] + redQ[nh][2] + redQ[nh][3];
    const float mu  = S * (1.0f / HH);
    const float var = (Q - (float)HH * mu * mu) * (1.0f / (HH - 1));
    const float inv = 1.0f / (sqrtf(var + EPSF) + EPSF);
    h_out[(size_t)node * HH + tt] = (gam[tt] * (v - mu) * inv + bet[tt]) * mask[node];
  }
#undef ZERO_ACC
#undef DO_GEMM_T
}

extern "C" void kernel_launch(void* const* d_in, const int* in_sizes, int n_in,
                              void* d_out, int out_size, void* d_ws, size_t ws_size,
                              hipStream_t stream) {
  const float* V     = (const float*)d_in[0];
  const float* E     = (const float*)d_in[1];
  const float* hS    = (const float*)d_in[2];
  const int*   Eidx  = (const int*)d_in[3];
  const float* mask  = (const float*)d_in[4];
  const float* Wv_w  = (const float*)d_in[5];
  const float* Wv_b  = (const float*)d_in[6];
  const float* Wv_g  = (const float*)d_in[7];
  const float* Wv_be = (const float*)d_in[8];
  const float* We_w  = (const float*)d_in[9];
  const float* We_b  = (const float*)d_in[10];
  const float* We_g  = (const float*)d_in[11];
  const float* We_be = (const float*)d_in[12];
  const float* LW1   = (const float*)d_in[13];
  const float* Lb1   = (const float*)d_in[14];
  const float* LW2   = (const float*)d_in[15];
  const float* Lb2   = (const float*)d_in[16];
  const float* LW3   = (const float*)d_in[17];
  const float* Lb3   = (const float*)d_in[18];
  const float* Lg    = (const float*)d_in[19];
  const float* Lbe   = (const float*)d_in[20];

  // ---- workspace layout (bytes) ----
  char* w = (char*)d_ws;
  unsigned short* he  = (unsigned short*)(w);                    // 65,536,000
  unsigned short* S1  = (unsigned short*)(w + 65536000);         //  6,144,000
  float* C1           = (float*)(w + 71680000);                  //  4,096,000
  unsigned short* G1  = (unsigned short*)(w + 75776000);         //  2,048,000
  unsigned short* WT  = (unsigned short*)(w + 77824000);         //    327,680 (10 mats)
  float* h0           = (float*)(w + 78151680);                  //  4,096,000
  float* h1           = (float*)(w + 82247680);                  //  4,096,000

  wconv_kernel<<<dim3(640), dim3(256), 0, stream>>>(LW1, LW2, LW3, We_w, WT);
  s1_kernel<<<dim3(750), dim3(256), 0, stream>>>(hS, LW1, S1);
  proj_ln_kernel<false><<<dim3((BB * NN) / KK), dim3(256), 0, stream>>>(
      V, Wv_w, Wv_b, Wv_g, Wv_be, (void*)h0);
  proj_ln_e_mfma<<<dim3((BB * NN * KK) / KK), dim3(256), 0, stream>>>(
      E, WT + (size_t)9 * HH * HH, We_b, We_g, We_be, he);

  const float* hin = h0;
  float* bufs[2] = { h1, h0 };
  for (int l = 0; l < DEPTHL; l++) {
    node_pre_kernel<<<dim3(250), dim3(256), 0, stream>>>(
        hin, LW1 + (size_t)l * 4 * HH * HH, Lb1 + (size_t)l * HH,
        S1 + (size_t)l * BB * NN * HH, C1, G1);
    float* out = (l == DEPTHL - 1) ? (float*)d_out : bufs[l & 1];
    edge_kernel<<<dim3(BB * NN / 2), dim3(512), 0, stream>>>(
        hin, he, Eidx, mask, C1, G1,
        WT + (size_t)(l * 3 + 0) * HH * HH,
        WT + (size_t)(l * 3 + 1) * HH * HH,
        WT + (size_t)(l * 3 + 2) * HH * HH,
        Lb2 + (size_t)l * HH, Lb3 + (size_t)l * HH,
        Lg + (size_t)l * HH, Lbe + (size_t)l * HH, out);
    hin = out;
  }
}

// Round 9
// 608.821 us; speedup vs baseline: 3.6732x; 1.1490x over previous
//
#include <hip/hip_runtime.h>
#include <hip/hip_bf16.h>

#define BB 4
#define NN 2000
#define KK 32
#define HH 128
#define DEPTHL 3
constexpr int   SS   = 132;      // padded LDS row stride (floats)
constexpr float EPSF = 1e-6f;
constexpr float INV_SCALE = 1.0f / 30.0f;

typedef __attribute__((ext_vector_type(8))) short bf16x8;   // 8 bf16 in 4 VGPRs
typedef __attribute__((ext_vector_type(4))) short bf16x4;   // 8 bytes
typedef __attribute__((ext_vector_type(4))) float f32x4;

__device__ __forceinline__ float bf2f(unsigned short u) {
  union { unsigned int i; float f; } v; v.i = ((unsigned int)u) << 16; return v.f;
}
__device__ __forceinline__ unsigned short f2bf(float f) {
  union { float f; unsigned int i; } v; v.f = f;
  unsigned int x = v.i;
  return (unsigned short)((x + 0x7FFFu + ((x >> 16) & 1u)) >> 16);
}

// Convert + transpose weights to bf16 WT[mat][col][k] (16384 elems per mat):
// mat 0..8  = l*3 + {W1e (LW1 rows 384..511), W2, W3}
// mat 9     = We_w^T
// mat 10    = Wv_w^T
// mat 11+m  (m=0..8): grp=m/3 (0:W1c rows 0..127, 1:W1v rows 128..255, 2:W1s rows 256..383), l=m%3
__global__ __launch_bounds__(256) void wconv_kernel(
    const float* __restrict__ LW1, const float* __restrict__ LW2,
    const float* __restrict__ LW3, const float* __restrict__ Wew,
    const float* __restrict__ Wvw, unsigned short* __restrict__ WT) {
  const int gid = blockIdx.x * 256 + threadIdx.x;
  const int mat = gid >> 14;
  const int rem = gid & 16383;
  const int col = rem >> 7;
  const int k   = rem & 127;
  float v;
  if (mat < 9) {
    const int l = mat / 3, wh = mat % 3;
    if (wh == 0)      v = LW1[(size_t)l * 4 * HH * HH + (size_t)(384 + k) * HH + col];
    else if (wh == 1) v = LW2[(size_t)l * HH * HH + (size_t)k * HH + col];
    else              v = LW3[(size_t)l * HH * HH + (size_t)k * HH + col];
  } else if (mat == 9) {
    v = Wew[(size_t)k * HH + col];
  } else if (mat == 10) {
    v = Wvw[(size_t)k * HH + col];
  } else {
    const int m = mat - 11;
    const int grp = m / 3, l = m % 3;
    v = LW1[(size_t)l * 4 * HH * HH + (size_t)(grp * 128 + k) * HH + col];
  }
  WT[gid] = f2bf(v);
}

// ---- MFMA fragment loaders ----
// fragment from swizzled LDS tile [32 rows][128 cols] bf16:
// returns tile[row = rf*16+lr][k = ks*32 + lg*8 .. +8]
__device__ __forceinline__ bf16x8 ldsA(const unsigned short* T, int rf, int ks, int lr, int lg) {
  const int row = rf * 16 + lr;
  const int boff = (row * 256 + ks * 64 + lg * 16) ^ ((row & 7) << 4);
  return *(const bf16x8*)((const char*)T + boff);
}
// fragment from global WT[col][k] (k contiguous)
__device__ __forceinline__ bf16x8 ldgB(const unsigned short* __restrict__ WT, int col, int ks, int lg) {
  return *(const bf16x8*)(WT + col * 128 + ks * 32 + lg * 8);
}

// stage one f32 row-segment (16 floats) into swizzled bf16 tile; t in [0,256)
__device__ __forceinline__ void stage_f32_tile(const float* __restrict__ src0,
                                               unsigned short* __restrict__ T, int t) {
  const int row = t >> 3, cb = (t & 7) * 16;
  const float* src = src0 + row * HH + cb;
  const float4 f0 = *(const float4*)(src);
  const float4 f1 = *(const float4*)(src + 4);
  const float4 f2 = *(const float4*)(src + 8);
  const float4 f3 = *(const float4*)(src + 12);
  bf16x8 u0, u1;
  u0[0] = (short)f2bf(f0.x); u0[1] = (short)f2bf(f0.y); u0[2] = (short)f2bf(f0.z); u0[3] = (short)f2bf(f0.w);
  u0[4] = (short)f2bf(f1.x); u0[5] = (short)f2bf(f1.y); u0[6] = (short)f2bf(f1.z); u0[7] = (short)f2bf(f1.w);
  u1[0] = (short)f2bf(f2.x); u1[1] = (short)f2bf(f2.y); u1[2] = (short)f2bf(f2.z); u1[3] = (short)f2bf(f2.w);
  u1[4] = (short)f2bf(f3.x); u1[5] = (short)f2bf(f3.y); u1[6] = (short)f2bf(f3.z); u1[7] = (short)f2bf(f3.w);
  const int base = row * 256 + cb * 2;
  const int sw = (row & 7) << 4;
  *(bf16x8*)((char*)T + (base ^ sw)) = u0;
  *(bf16x8*)((char*)T + ((base + 16) ^ sw)) = u1;
}

// ---------- MFMA row-projection + LayerNorm: 32 rows/block ----------
// out = LN(X @ W + bias); OUT_BF16 picks output type (bf16 he / f32 h)
template <bool OUT_BF16>
__global__ __launch_bounds__(256) void proj_ln_x_mfma(
    const float* __restrict__ X, const unsigned short* __restrict__ WxT,
    const float* __restrict__ bias, const float* __restrict__ gam,
    const float* __restrict__ bet, void* __restrict__ outp) {
  __shared__ unsigned short T0[KK * HH];
  __shared__ float yb[KK * SS];
  __shared__ float biasS[HH];
  const int t = threadIdx.x;
  const size_t row0 = (size_t)blockIdx.x * KK;

  stage_f32_tile(X + row0 * HH, T0, t);
  if (t < HH) biasS[t] = bias[t];
  __syncthreads();

  const int lane = t & 63, wid = t >> 6, lr = lane & 15, lg = lane >> 4;
  const int wbase = wid * 32;
  f32x4 a00 = (f32x4){0.f,0.f,0.f,0.f}, a01 = a00, a10 = a00, a11 = a00;
#pragma unroll
  for (int ks = 0; ks < 4; ks++) {
    const bf16x8 fw0 = ldgB(WxT, wbase + lr, ks, lg);
    const bf16x8 fw1 = ldgB(WxT, wbase + 16 + lr, ks, lg);
    const bf16x8 ft0 = ldsA(T0, 0, ks, lr, lg);
    const bf16x8 ft1 = ldsA(T0, 1, ks, lr, lg);
    a00 = __builtin_amdgcn_mfma_f32_16x16x32_bf16(fw0, ft0, a00, 0, 0, 0);
    a01 = __builtin_amdgcn_mfma_f32_16x16x32_bf16(fw0, ft1, a01, 0, 0, 0);
    a10 = __builtin_amdgcn_mfma_f32_16x16x32_bf16(fw1, ft0, a10, 0, 0, 0);
    a11 = __builtin_amdgcn_mfma_f32_16x16x32_bf16(fw1, ft1, a11, 0, 0, 0);
  }
  // D = [outcol x row]; lane holds row = b*16+lr, outcols col0..col0+3
#pragma unroll
  for (int a = 0; a < 2; a++) {
    const int col0 = wbase + a * 16 + lg * 4;
    const float4 bv = *(const float4*)(biasS + col0);
#pragma unroll
    for (int b = 0; b < 2; b++) {
      const int row = b * 16 + lr;
      const f32x4 ac = a == 0 ? (b == 0 ? a00 : a01) : (b == 0 ? a10 : a11);
      float4 y; y.x = ac[0] + bv.x; y.y = ac[1] + bv.y; y.z = ac[2] + bv.z; y.w = ac[3] + bv.w;
      *(float4*)(yb + row * SS + col0) = y;
    }
  }
  __syncthreads();

  const int r = t >> 3, g8 = t & 7;
  float s = 0.f, q = 0.f;
#pragma unroll
  for (int ii = 0; ii < 4; ii++) {
    const int c = (g8 + 8 * ii) * 4;
    const float4 y = *(const float4*)(yb + r * SS + c);
    s += y.x + y.y + y.z + y.w;
    q += y.x * y.x + y.y * y.y + y.z * y.z + y.w * y.w;
  }
  s += __shfl_xor(s, 1); q += __shfl_xor(q, 1);
  s += __shfl_xor(s, 2); q += __shfl_xor(q, 2);
  s += __shfl_xor(s, 4); q += __shfl_xor(q, 4);
  const float mu  = s * (1.0f / HH);
  const float var = (q - (float)HH * mu * mu) * (1.0f / (HH - 1));
  const float inv = 1.0f / (sqrtf(var + EPSF) + EPSF);
#pragma unroll
  for (int ii = 0; ii < 4; ii++) {
    const int c = (g8 + 8 * ii) * 4;
    const float4 y = *(const float4*)(yb + r * SS + c);
    const float o0 = gam[c + 0] * (y.x - mu) * inv + bet[c + 0];
    const float o1 = gam[c + 1] * (y.y - mu) * inv + bet[c + 1];
    const float o2 = gam[c + 2] * (y.z - mu) * inv + bet[c + 2];
    const float o3 = gam[c + 3] * (y.w - mu) * inv + bet[c + 3];
    if (OUT_BF16) {
      ushort4 u;
      u.x = f2bf(o0); u.y = f2bf(o1); u.z = f2bf(o2); u.w = f2bf(o3);
      *(ushort4*)((unsigned short*)outp + (row0 + r) * HH + c) = u;
    } else {
      float4 o; o.x = o0; o.y = o1; o.z = o2; o.w = o3;
      *(float4*)((float*)outp + (row0 + r) * HH + c) = o;
    }
  }
}

// ---------- MFMA per-layer node precompute: 32 node-rows/block ----------
// C1 = h @ W1c + b1 (f32); G1 = h @ W1v + hS @ W1s (bf16)
__global__ __launch_bounds__(256) void node_pre_mfma(
    const float* __restrict__ h_in, const float* __restrict__ hS,
    const unsigned short* __restrict__ W1cT, const unsigned short* __restrict__ W1vT,
    const unsigned short* __restrict__ W1sT, const float* __restrict__ b1,
    float* __restrict__ C1, unsigned short* __restrict__ G1) {
  __shared__ unsigned short Th[KK * HH];
  __shared__ unsigned short Ts[KK * HH];
  __shared__ float b1s[HH];
  const int t = threadIdx.x;
  const size_t row0 = (size_t)blockIdx.x * KK;

  stage_f32_tile(h_in + row0 * HH, Th, t);
  stage_f32_tile(hS + row0 * HH, Ts, t);
  if (t < HH) b1s[t] = b1[t];
  __syncthreads();

  const int lane = t & 63, wid = t >> 6, lr = lane & 15, lg = lane >> 4;
  const int wbase = wid * 32;
  f32x4 a00, a01, a10, a11;

  // ---- C1 = h @ W1c + b1 ----
  a00 = (f32x4){0.f,0.f,0.f,0.f}; a01 = a00; a10 = a00; a11 = a00;
#pragma unroll
  for (int ks = 0; ks < 4; ks++) {
    const bf16x8 fw0 = ldgB(W1cT, wbase + lr, ks, lg);
    const bf16x8 fw1 = ldgB(W1cT, wbase + 16 + lr, ks, lg);
    const bf16x8 ft0 = ldsA(Th, 0, ks, lr, lg);
    const bf16x8 ft1 = ldsA(Th, 1, ks, lr, lg);
    a00 = __builtin_amdgcn_mfma_f32_16x16x32_bf16(fw0, ft0, a00, 0, 0, 0);
    a01 = __builtin_amdgcn_mfma_f32_16x16x32_bf16(fw0, ft1, a01, 0, 0, 0);
    a10 = __builtin_amdgcn_mfma_f32_16x16x32_bf16(fw1, ft0, a10, 0, 0, 0);
    a11 = __builtin_amdgcn_mfma_f32_16x16x32_bf16(fw1, ft1, a11, 0, 0, 0);
  }
#pragma unroll
  for (int a = 0; a < 2; a++) {
    const int col0 = wbase + a * 16 + lg * 4;
    const float4 bv = *(const float4*)(b1s + col0);
#pragma unroll
    for (int b = 0; b < 2; b++) {
      const int row = b * 16 + lr;
      const f32x4 ac = a == 0 ? (b == 0 ? a00 : a01) : (b == 0 ? a10 : a11);
      float4 y; y.x = ac[0] + bv.x; y.y = ac[1] + bv.y; y.z = ac[2] + bv.z; y.w = ac[3] + bv.w;
      *(float4*)(C1 + (row0 + row) * HH + col0) = y;
    }
  }

  // ---- G1 = h @ W1v + hS @ W1s (accumulate both GEMMs in the same acc) ----
  a00 = (f32x4){0.f,0.f,0.f,0.f}; a01 = a00; a10 = a00; a11 = a00;
#pragma unroll
  for (int ks = 0; ks < 4; ks++) {
    const bf16x8 fw0 = ldgB(W1vT, wbase + lr, ks, lg);
    const bf16x8 fw1 = ldgB(W1vT, wbase + 16 + lr, ks, lg);
    const bf16x8 ft0 = ldsA(Th, 0, ks, lr, lg);
    const bf16x8 ft1 = ldsA(Th, 1, ks, lr, lg);
    a00 = __builtin_amdgcn_mfma_f32_16x16x32_bf16(fw0, ft0, a00, 0, 0, 0);
    a01 = __builtin_amdgcn_mfma_f32_16x16x32_bf16(fw0, ft1, a01, 0, 0, 0);
    a10 = __builtin_amdgcn_mfma_f32_16x16x32_bf16(fw1, ft0, a10, 0, 0, 0);
    a11 = __builtin_amdgcn_mfma_f32_16x16x32_bf16(fw1, ft1, a11, 0, 0, 0);
  }
#pragma unroll
  for (int ks = 0; ks < 4; ks++) {
    const bf16x8 fw0 = ldgB(W1sT, wbase + lr, ks, lg);
    const bf16x8 fw1 = ldgB(W1sT, wbase + 16 + lr, ks, lg);
    const bf16x8 ft0 = ldsA(Ts, 0, ks, lr, lg);
    const bf16x8 ft1 = ldsA(Ts, 1, ks, lr, lg);
    a00 = __builtin_amdgcn_mfma_f32_16x16x32_bf16(fw0, ft0, a00, 0, 0, 0);
    a01 = __builtin_amdgcn_mfma_f32_16x16x32_bf16(fw0, ft1, a01, 0, 0, 0);
    a10 = __builtin_amdgcn_mfma_f32_16x16x32_bf16(fw1, ft0, a10, 0, 0, 0);
    a11 = __builtin_amdgcn_mfma_f32_16x16x32_bf16(fw1, ft1, a11, 0, 0, 0);
  }
#pragma unroll
  for (int a = 0; a < 2; a++) {
    const int col0 = wbase + a * 16 + lg * 4;
#pragma unroll
    for (int b = 0; b < 2; b++) {
      const int row = b * 16 + lr;
      const f32x4 ac = a == 0 ? (b == 0 ? a00 : a01) : (b == 0 ? a10 : a11);
      uint2 pv;
      pv.x = (unsigned)f2bf(ac[0]) | ((unsigned)f2bf(ac[1]) << 16);
      pv.y = (unsigned)f2bf(ac[2]) | ((unsigned)f2bf(ac[3]) << 16);
      *(uint2*)(G1 + (row0 + row) * HH + col0) = pv;
    }
  }
}

// ---------------- MFMA per-edge kernel: TWO nodes per block ----------------
// LDS cut: m1 is written into G1s (dead after GEMM1 epilogue) -> ~36KB -> 4 blocks/CU
__global__ __launch_bounds__(512, 8) void edge_kernel(
    const float* __restrict__ h_in, const unsigned short* __restrict__ he,
    const int* __restrict__ E_idx, const float* __restrict__ mask,
    const float* __restrict__ C1, const unsigned short* __restrict__ G1,
    const unsigned short* __restrict__ WT1e, const unsigned short* __restrict__ WT2,
    const unsigned short* __restrict__ WT3,
    const float* __restrict__ b2, const float* __restrict__ b3,
    const float* __restrict__ gam, const float* __restrict__ bet,
    float* __restrict__ h_out) {
  __shared__ unsigned short T0[2][KK * HH];   // he -> later m2 (bf16, XOR-swizzled)
  __shared__ unsigned short G1s[2][KK * HH];  // gathered G1 -> later m1
  __shared__ float C1s[2][HH], dhs[2][HH];
  __shared__ float b2s[HH], b3s[HH];
  __shared__ float svm[2][KK];
  __shared__ float redS[2][4], redQ[2][4];

  const int t = threadIdx.x;
  const int nh = t >> 8, tt = t & 255;
  const int node = blockIdx.x * 2 + nh;
  const int bbase = (node / NN) * NN;

  // ---- staging ----
  {
    const int row = tt >> 3, cb = (tt & 7) * 16;
    const unsigned short* hrow = he + ((size_t)node * KK + row) * HH + cb;
    const bf16x8 e0 = *(const bf16x8*)hrow;
    const bf16x8 e1 = *(const bf16x8*)(hrow + 8);
    const int base = row * 256 + cb * 2;
    const int sw = (row & 7) << 4;
    *(bf16x8*)((char*)T0[nh] + (base ^ sw)) = e0;
    *(bf16x8*)((char*)T0[nh] + ((base + 16) ^ sw)) = e1;
    const int nb = E_idx[(size_t)node * KK + row];
    const unsigned short* gsrc = G1 + (size_t)(bbase + nb) * HH + cb;
    const bf16x8 g0 = *(const bf16x8*)gsrc;
    const bf16x8 g1 = *(const bf16x8*)(gsrc + 8);
    *(bf16x8*)((char*)G1s[nh] + (base ^ sw)) = g0;
    *(bf16x8*)((char*)G1s[nh] + ((base + 16) ^ sw)) = g1;
  }
  if (tt < HH) C1s[nh][tt] = C1[(size_t)node * HH + tt];
  if (t < HH) b2s[t] = b2[t];
  else if (t < 2 * HH) b3s[t - HH] = b3[t - HH];
  if (tt < KK) svm[nh][tt] = mask[bbase + E_idx[(size_t)node * KK + tt]];
  __syncthreads();

  const int lane = tt & 63, wid = tt >> 6, lr = lane & 15, lg = lane >> 4;
  const int wbase = wid * 32;
  f32x4 a00, a01, a10, a11;

#define ZERO_ACC() do { a00 = (f32x4){0.f,0.f,0.f,0.f}; a01 = a00; a10 = a00; a11 = a00; } while (0)
// Transposed form: A = weight frags (rows = outcols), B = tile frags (cols = edges)
#define DO_GEMM_T(TILE, WTm) do {                                          \
    _Pragma("unroll")                                                      \
    for (int ks = 0; ks < 4; ks++) {                                       \
      const bf16x8 fw0 = ldgB(WTm, wbase + lr, ks, lg);                    \
      const bf16x8 fw1 = ldgB(WTm, wbase + 16 + lr, ks, lg);               \
      const bf16x8 ft0 = ldsA(TILE, 0, ks, lr, lg);                        \
      const bf16x8 ft1 = ldsA(TILE, 1, ks, lr, lg);                        \
      a00 = __builtin_amdgcn_mfma_f32_16x16x32_bf16(fw0, ft0, a00, 0, 0, 0); \
      a01 = __builtin_amdgcn_mfma_f32_16x16x32_bf16(fw0, ft1, a01, 0, 0, 0); \
      a10 = __builtin_amdgcn_mfma_f32_16x16x32_bf16(fw1, ft0, a10, 0, 0, 0); \
      a11 = __builtin_amdgcn_mfma_f32_16x16x32_bf16(fw1, ft1, a11, 0, 0, 0); \
    } } while (0)

  // ---- GEMM1 (transposed): m1 = relu(he @ W1e + C1 + G1gather) -> G1s (in place) ----
  ZERO_ACC();
  DO_GEMM_T(T0[nh], WT1e);
#pragma unroll
  for (int a = 0; a < 2; a++) {
    const int col0 = wbase + a * 16 + lg * 4;
    const float4 c1v = *(const float4*)(&C1s[nh][col0]);
#pragma unroll
    for (int b = 0; b < 2; b++) {
      const int edge = b * 16 + lr;
      const int boff = (edge * 256 + col0 * 2) ^ ((edge & 7) << 4);
      const bf16x4 g = *(const bf16x4*)((const char*)G1s[nh] + boff);
      const f32x4 ac = a == 0 ? (b == 0 ? a00 : a01) : (b == 0 ? a10 : a11);
      const float x0 = fmaxf(ac[0] + c1v.x + bf2f((unsigned short)g[0]), 0.f);
      const float x1 = fmaxf(ac[1] + c1v.y + bf2f((unsigned short)g[1]), 0.f);
      const float x2 = fmaxf(ac[2] + c1v.z + bf2f((unsigned short)g[2]), 0.f);
      const float x3 = fmaxf(ac[3] + c1v.w + bf2f((unsigned short)g[3]), 0.f);
      uint2 pv;
      pv.x = (unsigned)f2bf(x0) | ((unsigned)f2bf(x1) << 16);
      pv.y = (unsigned)f2bf(x2) | ((unsigned)f2bf(x3) << 16);
      *(uint2*)((char*)G1s[nh] + boff) = pv;   // same boff this thread just read
    }
  }
  __syncthreads();

  // ---- GEMM2 (transposed): m2 = relu(m1 @ W2 + b2) -> T0 ----
  ZERO_ACC();
  DO_GEMM_T(G1s[nh], WT2);
#pragma unroll
  for (int a = 0; a < 2; a++) {
    const int col0 = wbase + a * 16 + lg * 4;
    const float4 bv = *(const float4*)(b2s + col0);
#pragma unroll
    for (int b = 0; b < 2; b++) {
      const int edge = b * 16 + lr;
      const int boff = (edge * 256 + col0 * 2) ^ ((edge & 7) << 4);
      const f32x4 ac = a == 0 ? (b == 0 ? a00 : a01) : (b == 0 ? a10 : a11);
      const float x0 = fmaxf(ac[0] + bv.x, 0.f);
      const float x1 = fmaxf(ac[1] + bv.y, 0.f);
      const float x2 = fmaxf(ac[2] + bv.z, 0.f);
      const float x3 = fmaxf(ac[3] + bv.w, 0.f);
      uint2 pv;
      pv.x = (unsigned)f2bf(x0) | ((unsigned)f2bf(x1) << 16);
      pv.y = (unsigned)f2bf(x2) | ((unsigned)f2bf(x3) << 16);
      *(uint2*)((char*)T0[nh] + boff) = pv;
    }
  }
  __syncthreads();

  // ---- GEMM3 (original form): m3 = m2 @ W3 + b3; mask; column-sum over edges ----
  ZERO_ACC();
  {
    const int col0 = wbase + lr, col1 = wbase + 16 + lr;
#pragma unroll
    for (int ks = 0; ks < 4; ks++) {
      const bf16x8 fa0 = ldsA(T0[nh], 0, ks, lr, lg);
      const bf16x8 fa1 = ldsA(T0[nh], 1, ks, lr, lg);
      const bf16x8 fb0 = ldgB(WT3, col0, ks, lg);
      const bf16x8 fb1 = ldgB(WT3, col1, ks, lg);
      a00 = __builtin_amdgcn_mfma_f32_16x16x32_bf16(fa0, fb0, a00, 0, 0, 0);
      a01 = __builtin_amdgcn_mfma_f32_16x16x32_bf16(fa0, fb1, a01, 0, 0, 0);
      a10 = __builtin_amdgcn_mfma_f32_16x16x32_bf16(fa1, fb0, a10, 0, 0, 0);
      a11 = __builtin_amdgcn_mfma_f32_16x16x32_bf16(fa1, fb1, a11, 0, 0, 0);
    }
    const float cb0 = b3s[col0], cb1 = b3s[col1];
    float s0 = 0.f, s1 = 0.f;
#pragma unroll
    for (int rf = 0; rf < 2; rf++) {
      const f32x4 v0 = rf ? a10 : a00;
      const f32x4 v1 = rf ? a11 : a01;
#pragma unroll
      for (int r = 0; r < 4; r++) {
        const int edge = rf * 16 + lg * 4 + r;
        const float vm = svm[nh][edge];
        s0 += vm * (v0[r] + cb0);
        s1 += vm * (v1[r] + cb1);
      }
    }
    s0 += __shfl_xor(s0, 16); s0 += __shfl_xor(s0, 32);
    s1 += __shfl_xor(s1, 16); s1 += __shfl_xor(s1, 32);
    if (lg == 0) { dhs[nh][col0] = s0; dhs[nh][col1] = s1; }
  }
  __syncthreads();

  // ---- residual + LayerNorm + mask ----
  float v = 0.f;
  if (tt < HH) v = h_in[(size_t)node * HH + tt] + dhs[nh][tt] * INV_SCALE;
  float s = (tt < HH) ? v : 0.f;
  float q = (tt < HH) ? v * v : 0.f;
#pragma unroll
  for (int off = 32; off >= 1; off >>= 1) { s += __shfl_xor(s, off); q += __shfl_xor(q, off); }
  if ((tt & 63) == 0) { redS[nh][tt >> 6] = s; redQ[nh][tt >> 6] = q; }
  __syncthreads();
  if (tt < HH) {
    const float S = redS[nh][0] + redS[nh][1] + redS[nh][2] + redS[nh][3];
    const float Q = redQ[nh][0] + redQ[nh][1] + redQ[nh][2] + redQ[nh][3];
    const float mu  = S * (1.0f / HH);
    const float var = (Q - (float)HH * mu * mu) * (1.0f / (HH - 1));
    const float inv = 1.0f / (sqrtf(var + EPSF) + EPSF);
    h_out[(size_t)node * HH + tt] = (gam[tt] * (v - mu) * inv + bet[tt]) * mask[node];
  }
#undef ZERO_ACC
#undef DO_GEMM_T
}

extern "C" void kernel_launch(void* const* d_in, const int* in_sizes, int n_in,
                              void* d_out, int out_size, void* d_ws, size_t ws_size,
                              hipStream_t stream) {
  const float* V     = (const float*)d_in[0];
  const float* E     = (const float*)d_in[1];
  const float* hS    = (const float*)d_in[2];
  const int*   Eidx  = (const int*)d_in[3];
  const float* mask  = (const float*)d_in[4];
  const float* Wv_w  = (const float*)d_in[5];
  const float* Wv_b  = (const float*)d_in[6];
  const float* Wv_g  = (const float*)d_in[7];
  const float* Wv_be = (const float*)d_in[8];
  const float* We_w  = (const float*)d_in[9];
  const float* We_b  = (const float*)d_in[10];
  const float* We_g  = (const float*)d_in[11];
  const float* We_be = (const float*)d_in[12];
  const float* LW1   = (const float*)d_in[13];
  const float* Lb1   = (const float*)d_in[14];
  const float* LW2   = (const float*)d_in[15];
  const float* Lb2   = (const float*)d_in[16];
  const float* LW3   = (const float*)d_in[17];
  const float* Lb3   = (const float*)d_in[18];
  const float* Lg    = (const float*)d_in[19];
  const float* Lbe   = (const float*)d_in[20];

  // ---- workspace layout (bytes) ----
  char* w = (char*)d_ws;
  unsigned short* he  = (unsigned short*)(w);                    // 65,536,000
  float* C1           = (float*)(w + 65536000);                  //  4,096,000
  unsigned short* G1  = (unsigned short*)(w + 69632000);         //  2,048,000
  unsigned short* WT  = (unsigned short*)(w + 71680000);         //    655,360 (20 mats)
  float* h0           = (float*)(w + 72335360);                  //  4,096,000
  float* h1           = (float*)(w + 76431360);                  //  4,096,000

  wconv_kernel<<<dim3(1280), dim3(256), 0, stream>>>(LW1, LW2, LW3, We_w, Wv_w, WT);
  proj_ln_x_mfma<false><<<dim3((BB * NN) / KK), dim3(256), 0, stream>>>(
      V, WT + (size_t)10 * HH * HH, Wv_b, Wv_g, Wv_be, (void*)h0);
  proj_ln_x_mfma<true><<<dim3((BB * NN * KK) / KK), dim3(256), 0, stream>>>(
      E, WT + (size_t)9 * HH * HH, We_b, We_g, We_be, (void*)he);

  const float* hin = h0;
  float* bufs[2] = { h1, h0 };
  for (int l = 0; l < DEPTHL; l++) {
    node_pre_mfma<<<dim3(250), dim3(256), 0, stream>>>(
        hin, hS,
        WT + (size_t)(11 + 0 * 3 + l) * HH * HH,   // W1cT
        WT + (size_t)(11 + 1 * 3 + l) * HH * HH,   // W1vT
        WT + (size_t)(11 + 2 * 3 + l) * HH * HH,   // W1sT
        Lb1 + (size_t)l * HH, C1, G1);
    float* out = (l == DEPTHL - 1) ? (float*)d_out : bufs[l & 1];
    edge_kernel<<<dim3(BB * NN / 2), dim3(512), 0, stream>>>(
        hin, he, Eidx, mask, C1, G1,
        WT + (size_t)(l * 3 + 0) * HH * HH,
        WT + (size_t)(l * 3 + 1) * HH * HH,
        WT + (size_t)(l * 3 + 2) * HH * HH,
        Lb2 + (size_t)l * HH, Lb3 + (size_t)l * HH,
        Lg + (size_t)l * HH, Lbe + (size_t)l * HH, out);
    hin = out;
  }
}